// Round 1
// baseline (286.210 us; speedup 1.0000x reference)
//
#include <hip/hip_runtime.h>
#include <hip/hip_bf16.h>

#define L_HW (128*128)

// ---- LDS layout (float offsets), buffers overlaid in time ----
// P1: Z[0,8192) XIN[8192,12288) W2[12288,28672) XCP[28672,36864)
// P2+: XC[8192,16512) (stride 65)  YM[16512,24832) (stride 65)
// P3+: DTLO[24832,25856) BM[25856,29952) CM[29952,34048)
// P5: WOUT[8192,16384) MU[34048,34112) RS[34112,34176)
#define Z_OFF    0
#define XIN_OFF  8192
#define W2_OFF   12288
#define XCP_OFF  28672
#define XC_OFF   8192
#define WOUT_OFF 8192
#define YM_OFF   16512
#define DTLO_OFF 24832
#define BM_OFF   25856
#define CM_OFF   29952
#define MU_OFF   34048
#define RS_OFF   34112
#define SMEM_FLOATS 36864

__global__ __launch_bounds__(512)
void ss2d_win_kernel(const float* __restrict__ x,
                     const float* __restrict__ in_proj_w,
                     const float* __restrict__ conv_w,
                     const float* __restrict__ conv_b,
                     const float* __restrict__ x_proj_w,
                     const float* __restrict__ dt_projs_w,
                     const float* __restrict__ dt_projs_b,
                     const float* __restrict__ A_logs,
                     const float* __restrict__ Ds,
                     const float* __restrict__ ln_g,
                     const float* __restrict__ ln_b,
                     const float* __restrict__ out_proj_w,
                     float* __restrict__ out)
{
    __shared__ float sm[SMEM_FLOATS];
    const int t = threadIdx.x;
    const int wid = blockIdx.x;
    const int b  = wid >> 8;
    const int ih = (wid >> 4) & 15;
    const int iw = wid & 15;
    const float* xwin = x + ((size_t)b*64)*L_HW + ih*8*128 + iw*8;

    // ---------- P0: stage x window as xin[m][p]; stage in_proj W swizzled ----------
    #pragma unroll
    for (int i = 0; i < 8; ++i) {
        int idx = i*512 + t;
        int m = idx >> 6, p = idx & 63;
        sm[XIN_OFF + m*64 + p] = xwin[(size_t)m*L_HW + (p>>3)*128 + (p&7)];
    }
    // W2[oc][chq'] float4 granules, col swizz: chq ^ ((oc>>3)&7)
    #pragma unroll
    for (int i = 0; i < 8; ++i) {
        int idx4 = i*512 + t;
        int oc = idx4 >> 4, chq = idx4 & 15;
        float4 v = *(const float4*)(in_proj_w + oc*64 + chq*4);
        *(float4*)(sm + W2_OFF + oc*64 + ((chq ^ ((oc>>3)&7))<<2)) = v;
    }
    __syncthreads();

    // ---------- P1: in_proj GEMM: xz[64px][256oc], 4px x 8oc per thread ----------
    {
        const int og = t & 31, pg = t >> 5;      // oc0 = og*8, px0 = pg*4
        const int oc0 = og*8, px0 = pg*4;
        const int wswz = og & 7;
        float acc[4][8];
        #pragma unroll
        for (int p = 0; p < 4; ++p)
            #pragma unroll
            for (int j = 0; j < 8; ++j) acc[p][j] = 0.f;
        #pragma unroll 4
        for (int chb = 0; chb < 16; ++chb) {
            float xr[4][4];
            #pragma unroll
            for (int cc = 0; cc < 4; ++cc) {
                float4 v = *(const float4*)(sm + XIN_OFF + (chb*4+cc)*64 + px0);
                xr[cc][0]=v.x; xr[cc][1]=v.y; xr[cc][2]=v.z; xr[cc][3]=v.w;
            }
            const int col = (chb ^ wswz) << 2;
            float wr[8][4];
            #pragma unroll
            for (int j = 0; j < 8; ++j) {
                float4 v = *(const float4*)(sm + W2_OFF + (oc0+j)*64 + col);
                wr[j][0]=v.x; wr[j][1]=v.y; wr[j][2]=v.z; wr[j][3]=v.w;
            }
            #pragma unroll
            for (int p = 0; p < 4; ++p)
                #pragma unroll
                for (int j = 0; j < 8; ++j)
                    acc[p][j] += xr[0][p]*wr[j][0] + xr[1][p]*wr[j][1]
                               + xr[2][p]*wr[j][2] + xr[3][p]*wr[j][3];
        }
        if (og < 16) { // xc half -> XCP (swizzled granules)
            const int col = (pg ^ (og & 7)) << 2;   // (d>>3)&7 == og&7
            #pragma unroll
            for (int j = 0; j < 8; ++j) {
                int d = oc0 + j;
                float4 v = make_float4(acc[0][j], acc[1][j], acc[2][j], acc[3][j]);
                *(float4*)(sm + XCP_OFF + d*64 + col) = v;
            }
        } else {      // z half -> Z (swizzled granules)
            const int col = (pg ^ ((og-16) & 7)) << 2;
            #pragma unroll
            for (int j = 0; j < 8; ++j) {
                int dz = oc0 - 128 + j;
                float4 v = make_float4(acc[0][j], acc[1][j], acc[2][j], acc[3][j]);
                *(float4*)(sm + Z_OFF + dz*64 + col) = v;
            }
        }
    }
    __syncthreads();

    // ---------- P2: depthwise 3x3 conv (zero pad in-window) + SiLU -> XC[d][p] s65 ----------
    {
        const int p = t & 63, dblk = (t >> 6) * 16;
        const int r = p >> 3, c = p & 7;
        #pragma unroll 2
        for (int i = 0; i < 16; ++i) {
            const int d = dblk + i;
            const int dsw = (d >> 3) & 7;
            const float* cw = conv_w + d*9;
            float acc = conv_b[d];
            #pragma unroll
            for (int ki = 0; ki < 3; ++ki) {
                int rr = r + ki - 1;
                if (rr < 0 || rr > 7) continue;
                #pragma unroll
                for (int kj = 0; kj < 3; ++kj) {
                    int cc2 = c + kj - 1;
                    if (cc2 < 0 || cc2 > 7) continue;
                    int pp = rr*8 + cc2;
                    acc += sm[XCP_OFF + d*64 + (((pp>>2) ^ dsw)<<2) + (pp&3)] * cw[ki*3+kj];
                }
            }
            sm[XC_OFF + d*65 + p] = acc / (1.f + __expf(-acc));  // silu
        }
    }
    __syncthreads();

    // ---------- P3: x_proj in pixel domain, scatter to scan order; zero YM ----------
    for (int i = t; i < 8320; i += 512) sm[YM_OFF + i] = 0.f;
    #pragma unroll 2
    for (int i = 0; i < 18; ++i) {
        int idx = i*512 + t;              // 9216 = (k,j,p)
        int k = idx / 2304;
        int rem = idx - k*2304;
        int j = rem >> 6, p = rem & 63;
        const float* wrow = x_proj_w + (k*36 + j)*128;
        float acc = 0.f;
        #pragma unroll 8
        for (int d = 0; d < 128; d += 4) {
            float4 wv = *(const float4*)(wrow + d);
            acc += wv.x * sm[XC_OFF + (d  )*65 + p]
                 + wv.y * sm[XC_OFF + (d+1)*65 + p]
                 + wv.z * sm[XC_OFF + (d+2)*65 + p]
                 + wv.w * sm[XC_OFF + (d+3)*65 + p];
        }
        int Tp = ((p & 7) << 3) | (p >> 3);
        int l = (k == 0) ? p : (k == 1) ? Tp : (k == 2) ? (63 - p) : (63 - Tp);
        if (j < 4)       sm[DTLO_OFF + (k<<8)  + j*64      + l] = acc;
        else if (j < 20) sm[BM_OFF   + (k<<10) + (j-4)*64  + l] = acc;
        else             sm[CM_OFF   + (k<<10) + (j-20)*64 + l] = acc;
    }
    __syncthreads();

    // ---------- P4: selective scan, one (k,d) per thread; merge via LDS atomics ----------
    {
        const int k = t >> 7, d = t & 127;
        const int kd = (k << 7) | d;
        float A[16];
        {
            const float4* ap = (const float4*)(A_logs + kd*16);
            #pragma unroll
            for (int q = 0; q < 4; ++q) {
                float4 v = ap[q];
                A[q*4+0] = -__expf(v.x); A[q*4+1] = -__expf(v.y);
                A[q*4+2] = -__expf(v.z); A[q*4+3] = -__expf(v.w);
            }
        }
        const float4 wv = *(const float4*)(dt_projs_w + kd*4);
        const float dtb = dt_projs_b[kd];
        const float Dv  = Ds[kd];
        float h[16];
        #pragma unroll
        for (int s = 0; s < 16; ++s) h[s] = 0.f;
        const float* dl = sm + DTLO_OFF + (k<<8);
        const float* Bb = sm + BM_OFF   + (k<<10);
        const float* Cb = sm + CM_OFF   + (k<<10);
        for (int l = 0; l < 64; ++l) {
            float dtraw = dtb + wv.x*dl[l] + wv.y*dl[64+l] + wv.z*dl[128+l] + wv.w*dl[192+l];
            float dt = (dtraw > 20.f) ? dtraw : __logf(1.f + __expf(dtraw)); // softplus
            int lr = 63 - l;
            int p = (k == 0) ? l
                  : (k == 1) ? (((l & 7) << 3) | (l >> 3))
                  : (k == 2) ? lr
                  : (((lr & 7) << 3) | (lr >> 3));
            float u = sm[XC_OFF + d*65 + p];
            float dtu = dt * u;
            float y = 0.f;
            #pragma unroll
            for (int s = 0; s < 16; ++s) {
                float dA = __expf(dt * A[s]);
                h[s] = fmaf(h[s], dA, dtu * Bb[s*64 + l]);
                y = fmaf(h[s], Cb[s*64 + l], y);
            }
            atomicAdd(&sm[YM_OFF + d*65 + p], y + Dv * u);
        }
    }
    __syncthreads();

    // ---------- P5a: LN stats (8 lanes per pixel) + stage out_proj ----------
    {
        const int px = t >> 3, j = t & 7;
        float s1 = 0.f, s2 = 0.f;
        #pragma unroll
        for (int i = 0; i < 16; ++i) {
            float v = sm[YM_OFF + (j*16 + i)*65 + px];
            s1 += v; s2 += v*v;
        }
        s1 += __shfl_xor(s1, 1); s2 += __shfl_xor(s2, 1);
        s1 += __shfl_xor(s1, 2); s2 += __shfl_xor(s2, 2);
        s1 += __shfl_xor(s1, 4); s2 += __shfl_xor(s2, 4);
        if (j == 0) {
            float mu = s1 * 0.0078125f;
            float var = s2 * 0.0078125f - mu*mu;
            sm[MU_OFF + px] = mu;
            sm[RS_OFF + px] = rsqrtf(var + 1e-5f);
        }
    }
    #pragma unroll
    for (int i = 0; i < 4; ++i) {           // WOUT[m][dq'] swizzled granules
        int idx4 = i*512 + t;
        int m = idx4 >> 5, dq = idx4 & 31;
        float4 v = *(const float4*)(out_proj_w + m*128 + dq*4);
        *(float4*)(sm + WOUT_OFF + m*128 + ((dq ^ ((m>>3)&7))<<2)) = v;
    }
    __syncthreads();

    // ---------- P5b: yhat = LN(y)*silu(z), in place over YM ----------
    {
        const int p = t & 63, dblk = (t >> 6) * 16;
        const float mu = sm[MU_OFF + p], rs = sm[RS_OFF + p];
        #pragma unroll 4
        for (int i = 0; i < 16; ++i) {
            int d = dblk + i;
            float yv = sm[YM_OFF + d*65 + p];
            float yh = (yv - mu) * rs * ln_g[d] + ln_b[d];
            float zv = sm[Z_OFF + d*64 + (((p>>2) ^ ((d>>3)&7))<<2) + (p&3)];
            sm[YM_OFF + d*65 + p] = yh * (zv / (1.f + __expf(-zv)));
        }
    }
    __syncthreads();

    // ---------- P5c: out_proj: out[p][m] = sum_d yhat[d][p]*Wout[m][d] ----------
    {
        const int p = t & 63, m0 = (t >> 6) * 8;
        const int swz = (m0 >> 3) & 7;
        float acc[8];
        #pragma unroll
        for (int j = 0; j < 8; ++j) acc[j] = 0.f;
        #pragma unroll 4
        for (int dq = 0; dq < 32; ++dq) {
            float y0 = sm[YM_OFF + (dq*4+0)*65 + p];
            float y1 = sm[YM_OFF + (dq*4+1)*65 + p];
            float y2 = sm[YM_OFF + (dq*4+2)*65 + p];
            float y3 = sm[YM_OFF + (dq*4+3)*65 + p];
            const int col = (dq ^ swz) << 2;
            #pragma unroll
            for (int j = 0; j < 8; ++j) {
                const float* wp = sm + WOUT_OFF + (m0+j)*128 + col;
                acc[j] += y0*wp[0] + y1*wp[1] + y2*wp[2] + y3*wp[3];
            }
        }
        float* op = out + ((size_t)b*64)*L_HW + (ih*8 + (p>>3))*128 + iw*8 + (p&7);
        #pragma unroll
        for (int j = 0; j < 8; ++j)
            op[(size_t)(m0+j)*L_HW] = acc[j];
    }
}

extern "C" void kernel_launch(void* const* d_in, const int* in_sizes, int n_in,
                              void* d_out, int out_size, void* d_ws, size_t ws_size,
                              hipStream_t stream) {
    const float* x          = (const float*)d_in[0];
    const float* in_proj_w  = (const float*)d_in[1];
    const float* conv_w     = (const float*)d_in[2];
    const float* conv_b     = (const float*)d_in[3];
    const float* x_proj_w   = (const float*)d_in[4];
    const float* dt_projs_w = (const float*)d_in[5];
    const float* dt_projs_b = (const float*)d_in[6];
    const float* A_logs     = (const float*)d_in[7];
    const float* Ds         = (const float*)d_in[8];
    const float* ln_g       = (const float*)d_in[9];
    const float* ln_b       = (const float*)d_in[10];
    const float* out_proj_w = (const float*)d_in[11];
    float* out = (float*)d_out;

    ss2d_win_kernel<<<dim3(512), dim3(512), 0, stream>>>(
        x, in_proj_w, conv_w, conv_b, x_proj_w, dt_projs_w, dt_projs_b,
        A_logs, Ds, ln_g, ln_b, out_proj_w, out);
}

// Round 2
// 267.612 us; speedup vs baseline: 1.0695x; 1.0695x over previous
//
#include <hip/hip_runtime.h>

#define L_HW (128*128)

__device__ __forceinline__ int transp(int p){ return ((p&7)<<3)|(p>>3); }

// ================= Kernel A: in_proj GEMM + dwconv + silu + x_proj =================
// LDS floats: XIN_T[64p][68] @0 (4352) ; WBUF[64oc][64ch] @4352 (4096)
//             XCP[128d][64p] swz @8448 (8192) ; XCT[64p][128d] swz @0 (overlays XIN+WBUF)
#define A_XIN  0
#define A_WBUF 4352
#define A_XCP  8448
#define A_XCT  0
#define A_SMEM 16640

__global__ __launch_bounds__(512)
void ka_front(const float* __restrict__ x,
              const float* __restrict__ in_proj_w,
              const float* __restrict__ conv_w,
              const float* __restrict__ conv_b,
              const float* __restrict__ x_proj_w,
              float* __restrict__ xct_g,   // [win][64p][128d]
              float* __restrict__ z_g,     // [win][128d][64p]
              float* __restrict__ xdbl_g)  // [win][4k][64l][36]
{
    __shared__ float sm[A_SMEM];
    const int t = threadIdx.x;
    const int win = blockIdx.x;
    const int b = win >> 8, ih = (win >> 4) & 15, iw = win & 15;
    const float* xwin = x + ((size_t)b*64)*L_HW + ih*8*128 + iw*8;

    // ---- stage XIN_T[p][ch] (stride 68) ----
    {
        const int ch = t >> 3, r = t & 7;
        const float* src = xwin + (size_t)ch*L_HW + r*128;
        float4 v0 = *(const float4*)(src);
        float4 v1 = *(const float4*)(src + 4);
        float* dst = sm + A_XIN + ch;
        const int p0 = r*8;
        dst[(p0+0)*68] = v0.x; dst[(p0+1)*68] = v0.y;
        dst[(p0+2)*68] = v0.z; dst[(p0+3)*68] = v0.w;
        dst[(p0+4)*68] = v1.x; dst[(p0+5)*68] = v1.y;
        dst[(p0+6)*68] = v1.z; dst[(p0+7)*68] = v1.w;
    }

    const int p  = t & 63;
    const int og = t >> 6;   // 0..7

    // ---- in_proj GEMM, 64 oc at a time (4 chunks: 0,1 -> xc ; 2,3 -> z) ----
    for (int c4 = 0; c4 < 4; ++c4) {
        __syncthreads();
        {
            const float* wsrc = in_proj_w + c4*4096;
            *(float4*)(sm + A_WBUF + t*4)       = *(const float4*)(wsrc + t*4);
            *(float4*)(sm + A_WBUF + (t+512)*4) = *(const float4*)(wsrc + (t+512)*4);
        }
        __syncthreads();
        float acc[8] = {0,0,0,0,0,0,0,0};
        #pragma unroll
        for (int chq = 0; chq < 16; ++chq) {
            float4 xv = *(const float4*)(sm + A_XIN + p*68 + chq*4);
            #pragma unroll
            for (int j = 0; j < 8; ++j) {
                float4 wv = *(const float4*)(sm + A_WBUF + (og*8+j)*64 + chq*4);
                acc[j] += xv.x*wv.x + xv.y*wv.y + xv.z*wv.z + xv.w*wv.w;
            }
        }
        if (c4 < 2) {
            const int dbase = c4*64 + og*8;
            #pragma unroll
            for (int j = 0; j < 8; ++j) {
                const int d = dbase + j;
                sm[A_XCP + d*64 + ((((p>>2) ^ (d&7))<<2) | (p&3))] = acc[j];
            }
        } else {
            const int dbase = (c4-2)*64 + og*8;
            float* zw = z_g + (size_t)win*8192 + p;
            #pragma unroll
            for (int j = 0; j < 8; ++j)
                zw[(size_t)(dbase+j)*64] = acc[j];
        }
    }
    __syncthreads();

    // ---- depthwise 3x3 conv (zero-pad in window) + silu -> XCT (swizzled [p][d]) ----
    {
        const int d = t >> 2, q = t & 3;
        const int ds7 = d & 7;
        float cw[9];
        #pragma unroll
        for (int i = 0; i < 9; ++i) cw[i] = conv_w[d*9 + i];
        const float cb = conv_b[d];
        #pragma unroll
        for (int jj = 0; jj < 16; ++jj) {
            const int pp = q*16 + jj;
            const int r = pp >> 3, c = pp & 7;
            float acc = cb;
            #pragma unroll
            for (int ki = 0; ki < 3; ++ki) {
                const int rr = r + ki - 1;
                if (rr < 0 || rr > 7) continue;
                #pragma unroll
                for (int kj = 0; kj < 3; ++kj) {
                    const int cc = c + kj - 1;
                    if (cc < 0 || cc > 7) continue;
                    const int pn = rr*8 + cc;
                    acc += sm[A_XCP + d*64 + ((((pn>>2) ^ ds7)<<2) | (pn&3))] * cw[ki*3+kj];
                }
            }
            const float v = acc / (1.f + __expf(-acc));
            sm[A_XCT + pp*128 + ((((d>>2) ^ (pp&7))<<2) | (d&3))] = v;
        }
    }
    __syncthreads();

    // ---- XCT -> global (coalesced, de-swizzled) ----
    {
        float* dst = xct_g + (size_t)win*8192;
        #pragma unroll
        for (int i = 0; i < 4; ++i) {
            const int G = i*512 + t;           // float4 index
            const int pp = G >> 5, dg = G & 31;
            float4 v = *(const float4*)(sm + A_XCT + pp*128 + ((dg ^ (pp&7))<<2));
            *(float4*)(dst + pp*128 + dg*4) = v;
        }
    }

    // ---- x_proj: per thread one (pixel p, k, half-of-36-rows); scatter to scan order ----
    {
        const int k = og & 3, jhalf = og >> 2;
        const int l = (k==0) ? p : (k==1) ? transp(p) : (k==2) ? (63-p) : (63 - transp(p));
        float* dstp = xdbl_g + ((size_t)((size_t)win*4 + k)*64 + l)*36;
        const float* wbase = x_proj_w + (size_t)k*36*128;
        if (jhalf == 0) {
            float acc[16] = {0};
            #pragma unroll 4
            for (int dg = 0; dg < 32; ++dg) {
                float4 xv = *(const float4*)(sm + A_XCT + p*128 + ((dg ^ (p&7))<<2));
                #pragma unroll
                for (int j = 0; j < 16; ++j) {
                    float4 wv = *(const float4*)(wbase + j*128 + dg*4);
                    acc[j] += xv.x*wv.x + xv.y*wv.y + xv.z*wv.z + xv.w*wv.w;
                }
            }
            #pragma unroll
            for (int j4 = 0; j4 < 4; ++j4)
                *(float4*)(dstp + j4*4) =
                    make_float4(acc[j4*4],acc[j4*4+1],acc[j4*4+2],acc[j4*4+3]);
        } else {
            float acc[20] = {0};
            #pragma unroll 4
            for (int dg = 0; dg < 32; ++dg) {
                float4 xv = *(const float4*)(sm + A_XCT + p*128 + ((dg ^ (p&7))<<2));
                #pragma unroll
                for (int j = 0; j < 20; ++j) {
                    float4 wv = *(const float4*)(wbase + (16+j)*128 + dg*4);
                    acc[j] += xv.x*wv.x + xv.y*wv.y + xv.z*wv.z + xv.w*wv.w;
                }
            }
            #pragma unroll
            for (int j4 = 0; j4 < 5; ++j4)
                *(float4*)(dstp + 16 + j4*4) =
                    make_float4(acc[j4*4],acc[j4*4+1],acc[j4*4+2],acc[j4*4+3]);
        }
    }
}

// ================= Kernel C: selective scan + merge + LN + gate + out_proj =================
#define C_YM 0          // [128][65]
#define C_MU 8320
#define C_RS 8384
#define C_SMEM 8448

__global__ __launch_bounds__(512)
void kc_scan(const float* __restrict__ xct_g,
             const float* __restrict__ z_g,
             const float* __restrict__ xdbl_g,
             const float* __restrict__ dt_projs_w,
             const float* __restrict__ dt_projs_b,
             const float* __restrict__ A_logs,
             const float* __restrict__ Ds,
             const float* __restrict__ ln_g,
             const float* __restrict__ ln_b,
             const float* __restrict__ out_proj_w,
             float* __restrict__ out)
{
    __shared__ float sm[C_SMEM];
    const int t = threadIdx.x;
    const int win = blockIdx.x;

    for (int i = t; i < 8320; i += 512) sm[C_YM + i] = 0.f;
    __syncthreads();

    // ---- scan: one (k,d) per thread; k is wave-uniform ----
    {
        const int k = t >> 7, d = t & 127, kd = t;
        float A[16];
        {
            const float4* ap = (const float4*)(A_logs + kd*16);
            #pragma unroll
            for (int q = 0; q < 4; ++q) {
                float4 v = ap[q];
                A[q*4+0] = -__expf(v.x); A[q*4+1] = -__expf(v.y);
                A[q*4+2] = -__expf(v.z); A[q*4+3] = -__expf(v.w);
            }
        }
        const float A0 = A[0];
        bool fast = true;
        #pragma unroll
        for (int s = 1; s < 16; ++s)
            fast = fast && (fabsf(A[s] - (float)(s+1)*A0) <= 1e-4f * fabsf(A[s]));
        const float4 wv = *(const float4*)(dt_projs_w + kd*4);
        const float dtb = dt_projs_b[kd];
        const float Dv  = Ds[kd];
        float h[16];
        #pragma unroll
        for (int s = 0; s < 16; ++s) h[s] = 0.f;
        const float* xd = xdbl_g + (size_t)((size_t)win*4 + k)*2304;
        const float* ub = xct_g + (size_t)win*8192 + d;

        for (int l = 0; l < 64; ++l) {
            const float* row = xd + l*36;
            float4 d0 = *(const float4*)(row);
            float4 b0 = *(const float4*)(row+4),  b1 = *(const float4*)(row+8);
            float4 b2 = *(const float4*)(row+12), b3 = *(const float4*)(row+16);
            float4 c0 = *(const float4*)(row+20), c1 = *(const float4*)(row+24);
            float4 c2 = *(const float4*)(row+28), c3 = *(const float4*)(row+32);
            float B16[16] = {b0.x,b0.y,b0.z,b0.w, b1.x,b1.y,b1.z,b1.w,
                             b2.x,b2.y,b2.z,b2.w, b3.x,b3.y,b3.z,b3.w};
            float C16[16] = {c0.x,c0.y,c0.z,c0.w, c1.x,c1.y,c1.z,c1.w,
                             c2.x,c2.y,c2.z,c2.w, c3.x,c3.y,c3.z,c3.w};
            float dtraw = dtb + wv.x*d0.x + wv.y*d0.y + wv.z*d0.z + wv.w*d0.w;
            float dt = (dtraw > 20.f) ? dtraw : __logf(1.f + __expf(dtraw));
            const int lr = 63 - l;
            const int p = (k==0) ? l : (k==1) ? transp(l) : (k==2) ? lr : transp(lr);
            const float u = ub[p*128];
            const float dtu = dt * u;
            float y = 0.f;
            if (fast) {
                const float r = __expf(dt * A0);
                float dA = r;
                #pragma unroll
                for (int s = 0; s < 16; ++s) {
                    h[s] = h[s]*dA + dtu*B16[s];
                    y += h[s]*C16[s];
                    dA *= r;
                }
            } else {
                #pragma unroll
                for (int s = 0; s < 16; ++s) {
                    const float dA = __expf(dt * A[s]);
                    h[s] = h[s]*dA + dtu*B16[s];
                    y += h[s]*C16[s];
                }
            }
            atomicAdd(&sm[C_YM + d*65 + p], y + Dv*u);
        }
    }
    __syncthreads();

    // ---- LN stats ----
    {
        const int px = t >> 3, j = t & 7;
        float s1 = 0.f, s2 = 0.f;
        #pragma unroll
        for (int i = 0; i < 16; ++i) {
            float v = sm[C_YM + (j*16+i)*65 + px];
            s1 += v; s2 += v*v;
        }
        s1 += __shfl_xor(s1,1); s2 += __shfl_xor(s2,1);
        s1 += __shfl_xor(s1,2); s2 += __shfl_xor(s2,2);
        s1 += __shfl_xor(s1,4); s2 += __shfl_xor(s2,4);
        if (j == 0) {
            float mu  = s1 * 0.0078125f;
            float var = s2 * 0.0078125f - mu*mu;
            sm[C_MU + px] = mu;
            sm[C_RS + px] = rsqrtf(var + 1e-5f);
        }
    }
    __syncthreads();

    // ---- yhat = LN(y)*silu(z), in place ----
    {
        const int p = t & 63, dblk = (t >> 6) * 16;
        const float mu = sm[C_MU + p], rs = sm[C_RS + p];
        const float* zb = z_g + (size_t)win*8192 + p;
        #pragma unroll 4
        for (int i = 0; i < 16; ++i) {
            const int d = dblk + i;
            float yv = sm[C_YM + d*65 + p];
            float yh = (yv - mu)*rs*ln_g[d] + ln_b[d];
            float zv = zb[(size_t)d*64];
            sm[C_YM + d*65 + p] = yh * (zv / (1.f + __expf(-zv)));
        }
    }
    __syncthreads();

    // ---- out_proj ----
    {
        const int p = t & 63, m0 = (t >> 6) * 8;
        float acc[8] = {0,0,0,0,0,0,0,0};
        #pragma unroll 4
        for (int dq = 0; dq < 32; ++dq) {
            float y0 = sm[C_YM + (dq*4+0)*65 + p];
            float y1 = sm[C_YM + (dq*4+1)*65 + p];
            float y2 = sm[C_YM + (dq*4+2)*65 + p];
            float y3 = sm[C_YM + (dq*4+3)*65 + p];
            #pragma unroll
            for (int j = 0; j < 8; ++j) {
                float4 wq = *(const float4*)(out_proj_w + (m0+j)*128 + dq*4);
                acc[j] += y0*wq.x + y1*wq.y + y2*wq.z + y3*wq.w;
            }
        }
        const int b = win >> 8, ih = (win>>4)&15, iw = win&15;
        float* op = out + ((size_t)b*64)*L_HW + (ih*8 + (p>>3))*128 + iw*8 + (p&7);
        #pragma unroll
        for (int j = 0; j < 8; ++j)
            op[(size_t)(m0+j)*L_HW] = acc[j];
    }
}

extern "C" void kernel_launch(void* const* d_in, const int* in_sizes, int n_in,
                              void* d_out, int out_size, void* d_ws, size_t ws_size,
                              hipStream_t stream) {
    const float* x          = (const float*)d_in[0];
    const float* in_proj_w  = (const float*)d_in[1];
    const float* conv_w     = (const float*)d_in[2];
    const float* conv_b     = (const float*)d_in[3];
    const float* x_proj_w   = (const float*)d_in[4];
    const float* dt_projs_w = (const float*)d_in[5];
    const float* dt_projs_b = (const float*)d_in[6];
    const float* A_logs     = (const float*)d_in[7];
    const float* Ds         = (const float*)d_in[8];
    const float* ln_g       = (const float*)d_in[9];
    const float* ln_b       = (const float*)d_in[10];
    const float* out_proj_w = (const float*)d_in[11];
    float* out = (float*)d_out;

    float* xct  = (float*)d_ws;            // 512*8192 floats
    float* zb   = xct + 4194304;           // 512*8192 floats
    float* xdbl = zb  + 4194304;           // 512*4*64*36 floats

    ka_front<<<dim3(512), dim3(512), 0, stream>>>(
        x, in_proj_w, conv_w, conv_b, x_proj_w, xct, zb, xdbl);
    kc_scan<<<dim3(512), dim3(512), 0, stream>>>(
        xct, zb, xdbl, dt_projs_w, dt_projs_b, A_logs, Ds, ln_g, ln_b,
        out_proj_w, out);
}